// Round 1
// baseline (512.160 us; speedup 1.0000x reference)
//
#include <hip/hip_runtime.h>
#include <hip/hip_bf16.h>
#include <stdint.h>

typedef __attribute__((ext_vector_type(8))) short short8;
typedef __attribute__((ext_vector_type(4))) float floatx4;

#define N_NODES 4096
#define BSD 48        // B*S = 4*12
#define CDIM 64
#define HDIM 128

#define AS1 __attribute__((address_space(1)))
#define AS3 __attribute__((address_space(3)))

__device__ __forceinline__ void gload_lds16(const void* g, void* l) {
    __builtin_amdgcn_global_load_lds((const AS1 void*)g, (AS3 void*)l, 16, 0, 0);
}

// ---------------- kernel 1: d[n] = rsqrt(rowsum(A) + 1) ----------------
__global__ __launch_bounds__(256) void k_rowsum(const float* __restrict__ A,
                                                float* __restrict__ dvec) {
    const int row = blockIdx.x;
    const float4* Ar = (const float4*)(A + (size_t)row * N_NODES);
    float s = 0.f;
    const int t = threadIdx.x;
    #pragma unroll
    for (int j = 0; j < 4; ++j) {
        float4 v = Ar[t + j * 256];
        s += v.x + v.y + v.z + v.w;
    }
    #pragma unroll
    for (int off = 32; off > 0; off >>= 1) s += __shfl_down(s, off, 64);
    __shared__ float ps[4];
    if ((t & 63) == 0) ps[t >> 6] = s;
    __syncthreads();
    if (t == 0) {
        float tot = ps[0] + ps[1] + ps[2] + ps[3];
        dvec[row] = rsqrtf(tot + 1.0f);
    }
}

// ------- kernel 2: Ab = bf16(A), outA = A (fused passthrough copy) -------
__global__ __launch_bounds__(256) void k_convA(const float* __restrict__ A,
                                               __hip_bfloat16* __restrict__ Ab,
                                               float* __restrict__ outA) {
    const int idx = blockIdx.x * 256 + threadIdx.x;   // float4 units, 4194304 total
    float4 v = ((const float4*)A)[idx];
    ((float4*)outA)[idx] = v;
    union { __hip_bfloat16 h[4]; short4 s4; } u;
    u.h[0] = __float2bfloat16(v.x);
    u.h[1] = __float2bfloat16(v.y);
    u.h[2] = __float2bfloat16(v.z);
    u.h[3] = __float2bfloat16(v.w);
    ((short4*)Ab)[idx] = u.s4;
}

// ------ kernel 3: Xt[(bs*64+c)][k] = bf16(d[k] * x[bs,k,c])  (K-major) ------
__global__ __launch_bounds__(256) void k_buildXt(const float* __restrict__ x,
                                                 const float* __restrict__ dvec,
                                                 __hip_bfloat16* __restrict__ Xt) {
    __shared__ float tile[64 * 65];
    __shared__ float dloc[64];
    const int t = threadIdx.x;
    const int bs = blockIdx.y;
    const int k0 = blockIdx.x * 64;
    const float* xp = x + ((size_t)bs * N_NODES + k0) * CDIM;  // 4096 contiguous floats
    const float4* xp4 = (const float4*)xp;
    #pragma unroll
    for (int it = 0; it < 4; ++it) {
        int q = it * 256 + t;          // float4 index, 1024 total
        float4 v = xp4[q];
        int p = q * 4;                 // element index: p = kk*64 + c
        int kk = p >> 6, c = p & 63;
        tile[kk * 65 + c + 0] = v.x;
        tile[kk * 65 + c + 1] = v.y;
        tile[kk * 65 + c + 2] = v.z;
        tile[kk * 65 + c + 3] = v.w;
    }
    if (t < 64) dloc[t] = dvec[k0 + t];
    __syncthreads();
    #pragma unroll
    for (int it = 0; it < 16; ++it) {
        int p = it * 256 + t;
        int c = p >> 6;      // 0..63
        int kk = p & 63;
        float v = tile[kk * 65 + c] * dloc[kk];
        Xt[(size_t)(bs * CDIM + c) * N_NODES + k0 + kk] = __float2bfloat16(v);
    }
}

// ------ kernel 4: GEMM Z[i][j] = sum_k Ab[i][k]*Xt[j][k]; G = bf16(x - d[i]*Z) ------
// m97 structure: 128x128 tile, BK=32, global_load_lds w16, 16x16x32 bf16 MFMA.
__global__ __launch_bounds__(256) void k_gemm(const __hip_bfloat16* __restrict__ Ab,
                                              const __hip_bfloat16* __restrict__ Xt,
                                              const float* __restrict__ x,
                                              const float* __restrict__ dvec,
                                              __hip_bfloat16* __restrict__ G) {
    __shared__ __hip_bfloat16 As[128 * 32];
    __shared__ __hip_bfloat16 Bs[128 * 32];
    const int t = threadIdx.x;
    const int w = t >> 6, l = t & 63;
    const int i0 = blockIdx.y * 128;
    const int j0 = blockIdx.x * 128;
    const int wm = w >> 1, wn = w & 1;
    const int ar = l & 15;
    const int kq = (l >> 4) * 8;

    const int srow = t >> 2;          // staging row 0..63 (chunk 1), +64 (chunk 2)
    const int skcol = (t & 3) * 8;

    floatx4 acc[4][4];
    #pragma unroll
    for (int a = 0; a < 4; ++a)
        #pragma unroll
        for (int b = 0; b < 4; ++b)
            acc[a][b] = (floatx4){0.f, 0.f, 0.f, 0.f};

    const __hip_bfloat16* gA0 = Ab + (size_t)(i0 + srow) * N_NODES + skcol;
    const __hip_bfloat16* gB0 = Xt + (size_t)(j0 + srow) * N_NODES + skcol;

    for (int k0 = 0; k0 < N_NODES; k0 += 32) {
        __syncthreads();
        gload_lds16(gA0 + k0,                    As + w * 512);
        gload_lds16(gA0 + (size_t)64 * N_NODES + k0, As + 2048 + w * 512);
        gload_lds16(gB0 + k0,                    Bs + w * 512);
        gload_lds16(gB0 + (size_t)64 * N_NODES + k0, Bs + 2048 + w * 512);
        __syncthreads();
        short8 af[4], bfr[4];
        #pragma unroll
        for (int mt = 0; mt < 4; ++mt)
            af[mt] = *(const short8*)(As + (wm * 64 + mt * 16 + ar) * 32 + kq);
        #pragma unroll
        for (int nt = 0; nt < 4; ++nt)
            bfr[nt] = *(const short8*)(Bs + (wn * 64 + nt * 16 + ar) * 32 + kq);
        #pragma unroll
        for (int mt = 0; mt < 4; ++mt)
            #pragma unroll
            for (int nt = 0; nt < 4; ++nt)
                acc[mt][nt] = __builtin_amdgcn_mfma_f32_16x16x32_bf16(
                    af[mt], bfr[nt], acc[mt][nt], 0, 0, 0);
    }

    // epilogue: G[bs,i,c] = bf16(x[bs,i,c] - d[i]*Z[i,j]),  j = bs*64 + c
    #pragma unroll
    for (int mt = 0; mt < 4; ++mt) {
        const int ibase = i0 + wm * 64 + mt * 16 + (l >> 4) * 4;
        #pragma unroll
        for (int nt = 0; nt < 4; ++nt) {
            const int j = j0 + wn * 64 + nt * 16 + (l & 15);
            const int bs = j >> 6, c = j & 63;
            #pragma unroll
            for (int r = 0; r < 4; ++r) {
                const int i = ibase + r;
                const size_t xi = ((size_t)bs * N_NODES + i) * CDIM + c;
                float g = x[xi] - dvec[i] * acc[mt][nt][r];
                G[xi] = __float2bfloat16(g);
            }
        }
    }
}

// ------ kernel 5: out[bs,i,h] = sigmoid(sum_c G[bs,i,c] * W[h,c]) ------
__global__ __launch_bounds__(256) void k_out(const __hip_bfloat16* __restrict__ G,
                                             const float* __restrict__ W,  // [128][64]
                                             float* __restrict__ out) {
    __shared__ float Wt[64 * 132];           // transposed, padded
    __shared__ __hip_bfloat16 Gs[32 * 64];
    const int t = threadIdx.x;
    const int bs = blockIdx.y;
    const int i0 = blockIdx.x * 32;
    #pragma unroll
    for (int it = 0; it < 32; ++it) {
        int p = it * 256 + t;                // 8192
        int h = p & 127, c = p >> 7;
        Wt[c * 132 + h] = W[h * 64 + c];
    }
    const short4* gp4 = (const short4*)(G + ((size_t)bs * N_NODES + i0) * CDIM);
    ((short4*)Gs)[t]       = gp4[t];
    ((short4*)Gs)[256 + t] = gp4[256 + t];
    __syncthreads();

    const int hg = t & 31;       // h0 = hg*4
    const int ig = t >> 5;       // 8 groups of 4 i
    float acc[4][4] = {};
    #pragma unroll
    for (int c = 0; c < 64; ++c) {
        float4 wv = *(const float4*)(Wt + c * 132 + hg * 4);
        #pragma unroll
        for (int ii = 0; ii < 4; ++ii) {
            float g = __bfloat162float(Gs[(ig * 4 + ii) * 64 + c]);
            acc[ii][0] += g * wv.x;
            acc[ii][1] += g * wv.y;
            acc[ii][2] += g * wv.z;
            acc[ii][3] += g * wv.w;
        }
    }
    #pragma unroll
    for (int ii = 0; ii < 4; ++ii) {
        const int i = i0 + ig * 4 + ii;
        float4 o;
        o.x = 1.f / (1.f + __expf(-acc[ii][0]));
        o.y = 1.f / (1.f + __expf(-acc[ii][1]));
        o.z = 1.f / (1.f + __expf(-acc[ii][2]));
        o.w = 1.f / (1.f + __expf(-acc[ii][3]));
        *(float4*)(out + ((size_t)bs * N_NODES + i) * HDIM + hg * 4) = o;
    }
}

extern "C" void kernel_launch(void* const* d_in, const int* in_sizes, int n_in,
                              void* d_out, int out_size, void* d_ws, size_t ws_size,
                              hipStream_t stream) {
    const float* x = (const float*)d_in[0];   // [48][4096][64]
    const float* A = (const float*)d_in[1];   // [4096][4096]
    const float* W = (const float*)d_in[2];   // [128][64]
    float* out  = (float*)d_out;              // out0: 25165824 floats
    float* outA = out + 25165824;             // A passthrough: 16777216 floats

    char* ws = (char*)d_ws;
    float* dvec = (float*)ws;
    const size_t offD  = 16384;
    const size_t szAb  = (size_t)16777216 * 2;   // 33554432
    const size_t szXt  = (size_t)3072 * 4096 * 2; // 25165824
    const size_t szG   = (size_t)48 * 4096 * 64 * 2; // 25165824

    __hip_bfloat16 *Ab, *Xt, *G;
    if (ws_size >= offD + szAb + szXt + szG) {
        Ab = (__hip_bfloat16*)(ws + offD);
        Xt = (__hip_bfloat16*)(ws + offD + szAb);
        G  = (__hip_bfloat16*)(ws + offD + szAb + szXt);
    } else {
        // out0 region (100 MB fp32) is dead until k_out; use it for Ab scratch.
        Ab = (__hip_bfloat16*)out;
        Xt = (__hip_bfloat16*)(ws + offD);
        G  = (__hip_bfloat16*)(ws + offD + szXt);
    }

    k_rowsum <<<4096, 256, 0, stream>>>(A, dvec);
    k_convA  <<<16384, 256, 0, stream>>>(A, Ab, outA);
    k_buildXt<<<dim3(64, 48), 256, 0, stream>>>(x, dvec, Xt);
    k_gemm   <<<dim3(24, 32), 256, 0, stream>>>(Ab, Xt, x, dvec, G);
    k_out    <<<dim3(128, 48), 256, 0, stream>>>(G, W, out);
}

// Round 2
// 448.237 us; speedup vs baseline: 1.1426x; 1.1426x over previous
//
#include <hip/hip_runtime.h>
#include <hip/hip_bf16.h>
#include <stdint.h>

typedef __attribute__((ext_vector_type(8))) short short8;
typedef __attribute__((ext_vector_type(4))) float floatx4;

#define N_NODES 4096
#define CDIM 64
#define HDIM 128

#define AS1 __attribute__((address_space(1)))
#define AS3 __attribute__((address_space(3)))

__device__ __forceinline__ void gload_lds16(const void* g, void* l) {
    __builtin_amdgcn_global_load_lds((const AS1 void*)g, (AS3 void*)l, 16, 0, 0);
}

// -------- kernel 1: fused rowsum + A passthrough copy + bf16 convert --------
// dvec[row] = rsqrt(rowsum(A)+1); outA = A; Ab = bf16(A). One read of A.
__global__ __launch_bounds__(256) void k_prep(const float* __restrict__ A,
                                              float* __restrict__ outA,
                                              __hip_bfloat16* __restrict__ Ab,
                                              float* __restrict__ dvec) {
    const int row = blockIdx.x;
    const int t = threadIdx.x;
    const float4* Ar = (const float4*)(A + (size_t)row * N_NODES);
    float4* Or = (float4*)(outA + (size_t)row * N_NODES);
    short4* Br = (short4*)(Ab + (size_t)row * N_NODES);
    float s = 0.f;
    #pragma unroll
    for (int j = 0; j < 4; ++j) {
        int q = t + j * 256;
        float4 v = Ar[q];
        Or[q] = v;
        union { __hip_bfloat16 h[4]; short4 s4; } u;
        u.h[0] = __float2bfloat16(v.x);
        u.h[1] = __float2bfloat16(v.y);
        u.h[2] = __float2bfloat16(v.z);
        u.h[3] = __float2bfloat16(v.w);
        Br[q] = u.s4;
        s += v.x + v.y + v.z + v.w;
    }
    #pragma unroll
    for (int off = 32; off > 0; off >>= 1) s += __shfl_down(s, off, 64);
    __shared__ float ps[4];
    if ((t & 63) == 0) ps[t >> 6] = s;
    __syncthreads();
    if (t == 0) {
        float tot = ps[0] + ps[1] + ps[2] + ps[3];
        dvec[row] = rsqrtf(tot + 1.0f);
    }
}

// ------ kernel 2: Xt[(bs*64+c)][k] = bf16(d[k] * x[bs,k,c])  (K-major) ------
__global__ __launch_bounds__(256) void k_buildXt(const float* __restrict__ x,
                                                 const float* __restrict__ dvec,
                                                 __hip_bfloat16* __restrict__ Xt) {
    __shared__ float tile[64 * 65];
    __shared__ float dloc[64];
    const int t = threadIdx.x;
    const int bs = blockIdx.y;
    const int k0 = blockIdx.x * 64;
    const float* xp = x + ((size_t)bs * N_NODES + k0) * CDIM;
    const float4* xp4 = (const float4*)xp;
    #pragma unroll
    for (int it = 0; it < 4; ++it) {
        int q = it * 256 + t;
        float4 v = xp4[q];
        int p = q * 4;
        int kk = p >> 6, c = p & 63;
        tile[kk * 65 + c + 0] = v.x;
        tile[kk * 65 + c + 1] = v.y;
        tile[kk * 65 + c + 2] = v.z;
        tile[kk * 65 + c + 3] = v.w;
    }
    if (t < 64) dloc[t] = dvec[k0 + t];
    __syncthreads();
    #pragma unroll
    for (int it = 0; it < 16; ++it) {
        int p = it * 256 + t;
        int c = p >> 6;
        int kk = p & 63;
        float v = tile[kk * 65 + c] * dloc[kk];
        Xt[(size_t)(bs * CDIM + c) * N_NODES + k0 + kk] = __float2bfloat16(v);
    }
}

// ------ kernel 3 (fused): Z = Ab·Xt^T; G = x - d*Z (LDS); out = sigmoid(G·W^T) ------
__global__ __launch_bounds__(256) void k_gemm_out(const __hip_bfloat16* __restrict__ Ab,
                                                  const __hip_bfloat16* __restrict__ Xt,
                                                  const float* __restrict__ x,
                                                  const float* __restrict__ dvec,
                                                  const float* __restrict__ W,
                                                  float* __restrict__ out) {
    // smem: main loop uses As/Bs (16 KB); epilogue reuses as Gs (36 KB) + Wbs (16 KB)
    __shared__ __align__(16) char smem[53248];
    __hip_bfloat16* As  = (__hip_bfloat16*)smem;            // [128*32]
    __hip_bfloat16* Bs  = (__hip_bfloat16*)(smem + 8192);   // [128*32]
    __hip_bfloat16* Gs  = (__hip_bfloat16*)smem;            // [2][128][72] (pad 72 for banks+align)
    __hip_bfloat16* Wbs = (__hip_bfloat16*)(smem + 36864);  // [128][64]

    const int t = threadIdx.x;
    const int w = t >> 6, l = t & 63;
    const int i0 = blockIdx.y * 128;
    const int j0 = blockIdx.x * 128;
    const int wm = w >> 1, wn = w & 1;
    const int ar = l & 15;
    const int kq = (l >> 4) * 8;
    const int col = l & 15;
    const int rowq = (l >> 4) * 4;

    const int srow = t >> 2;
    const int skcol = (t & 3) * 8;

    // stage W into LDS as bf16 [h][c] (doesn't alias As/Bs; done once, pre-loop)
    {
        const float4* W4 = (const float4*)W;   // 2048 float4
        #pragma unroll
        for (int it = 0; it < 8; ++it) {
            int q4 = it * 256 + t;
            float4 v = W4[q4];
            int p = q4 * 4;          // = h*64 + c, c%4==0
            union { __hip_bfloat16 h[4]; short4 s4; } u;
            u.h[0] = __float2bfloat16(v.x);
            u.h[1] = __float2bfloat16(v.y);
            u.h[2] = __float2bfloat16(v.z);
            u.h[3] = __float2bfloat16(v.w);
            *(short4*)(Wbs + p) = u.s4;
        }
    }

    floatx4 acc[4][4];
    #pragma unroll
    for (int a = 0; a < 4; ++a)
        #pragma unroll
        for (int b = 0; b < 4; ++b)
            acc[a][b] = (floatx4){0.f, 0.f, 0.f, 0.f};

    const __hip_bfloat16* gA0 = Ab + (size_t)(i0 + srow) * N_NODES + skcol;
    const __hip_bfloat16* gB0 = Xt + (size_t)(j0 + srow) * N_NODES + skcol;

    for (int k0 = 0; k0 < N_NODES; k0 += 32) {
        __syncthreads();
        gload_lds16(gA0 + k0,                        As + w * 512);
        gload_lds16(gA0 + (size_t)64 * N_NODES + k0, As + 2048 + w * 512);
        gload_lds16(gB0 + k0,                        Bs + w * 512);
        gload_lds16(gB0 + (size_t)64 * N_NODES + k0, Bs + 2048 + w * 512);
        __syncthreads();
        short8 af[4], bfr[4];
        #pragma unroll
        for (int mt = 0; mt < 4; ++mt)
            af[mt] = *(const short8*)(As + (wm * 64 + mt * 16 + ar) * 32 + kq);
        #pragma unroll
        for (int nt = 0; nt < 4; ++nt)
            bfr[nt] = *(const short8*)(Bs + (wn * 64 + nt * 16 + ar) * 32 + kq);
        #pragma unroll
        for (int mt = 0; mt < 4; ++mt)
            #pragma unroll
            for (int nt = 0; nt < 4; ++nt)
                acc[mt][nt] = __builtin_amdgcn_mfma_f32_16x16x32_bf16(
                    af[mt], bfr[nt], acc[mt][nt], 0, 0, 0);
    }

    // ---- epilogue stage 1: G = bf16(x - d*Z) into Gs (overwrites As/Bs) ----
    __syncthreads();
    #pragma unroll
    for (int mt = 0; mt < 4; ++mt) {
        const int irel_base = wm * 64 + mt * 16 + rowq;
        #pragma unroll
        for (int nt = 0; nt < 4; ++nt) {
            const int jj = wn * 64 + nt * 16 + col;    // 0..127
            const int bsr = jj >> 6, c = jj & 63;
            const int bs_abs = blockIdx.x * 2 + bsr;
            #pragma unroll
            for (int r = 0; r < 4; ++r) {
                const int irel = irel_base + r;
                const int i = i0 + irel;
                const size_t xi = ((size_t)bs_abs * N_NODES + i) * CDIM + c;
                float g = x[xi] - dvec[i] * acc[mt][nt][r];
                Gs[bsr * 9216 + irel * 72 + c] = __float2bfloat16(g);
            }
        }
    }
    __syncthreads();

    // ---- epilogue stage 2: out = sigmoid(G · W^T) via MFMA, per bs ----
    #pragma unroll
    for (int bsr = 0; bsr < 2; ++bsr) {
        const int bs_abs = blockIdx.x * 2 + bsr;
        floatx4 o[4][4];
        #pragma unroll
        for (int a = 0; a < 4; ++a)
            #pragma unroll
            for (int b = 0; b < 4; ++b)
                o[a][b] = (floatx4){0.f, 0.f, 0.f, 0.f};
        #pragma unroll
        for (int ks = 0; ks < 2; ++ks) {
            const int kk = ks * 32 + kq;
            short8 gf[4], wf[4];
            #pragma unroll
            for (int mt = 0; mt < 4; ++mt)
                gf[mt] = *(const short8*)(Gs + bsr * 9216 + (wm * 64 + mt * 16 + ar) * 72 + kk);
            #pragma unroll
            for (int nt = 0; nt < 4; ++nt)
                wf[nt] = *(const short8*)(Wbs + (wn * 64 + nt * 16 + ar) * 64 + kk);
            #pragma unroll
            for (int mt = 0; mt < 4; ++mt)
                #pragma unroll
                for (int nt = 0; nt < 4; ++nt)
                    o[mt][nt] = __builtin_amdgcn_mfma_f32_16x16x32_bf16(
                        gf[mt], wf[nt], o[mt][nt], 0, 0, 0);
        }
        #pragma unroll
        for (int mt = 0; mt < 4; ++mt) {
            #pragma unroll
            for (int nt = 0; nt < 4; ++nt) {
                const int h = wn * 64 + nt * 16 + col;
                #pragma unroll
                for (int r = 0; r < 4; ++r) {
                    const int i = i0 + wm * 64 + mt * 16 + rowq + r;
                    float v = 1.f / (1.f + __expf(-o[mt][nt][r]));
                    out[((size_t)bs_abs * N_NODES + i) * HDIM + h] = v;
                }
            }
        }
    }
}

// -------- legacy fallback path (small workspace): gemm->G, then k_out --------
__global__ __launch_bounds__(256) void k_gemm(const __hip_bfloat16* __restrict__ Ab,
                                              const __hip_bfloat16* __restrict__ Xt,
                                              const float* __restrict__ x,
                                              const float* __restrict__ dvec,
                                              __hip_bfloat16* __restrict__ G) {
    __shared__ __hip_bfloat16 As[128 * 32];
    __shared__ __hip_bfloat16 Bs[128 * 32];
    const int t = threadIdx.x;
    const int w = t >> 6, l = t & 63;
    const int i0 = blockIdx.y * 128;
    const int j0 = blockIdx.x * 128;
    const int wm = w >> 1, wn = w & 1;
    const int ar = l & 15;
    const int kq = (l >> 4) * 8;
    const int srow = t >> 2;
    const int skcol = (t & 3) * 8;

    floatx4 acc[4][4];
    #pragma unroll
    for (int a = 0; a < 4; ++a)
        #pragma unroll
        for (int b = 0; b < 4; ++b)
            acc[a][b] = (floatx4){0.f, 0.f, 0.f, 0.f};

    const __hip_bfloat16* gA0 = Ab + (size_t)(i0 + srow) * N_NODES + skcol;
    const __hip_bfloat16* gB0 = Xt + (size_t)(j0 + srow) * N_NODES + skcol;

    for (int k0 = 0; k0 < N_NODES; k0 += 32) {
        __syncthreads();
        gload_lds16(gA0 + k0,                        As + w * 512);
        gload_lds16(gA0 + (size_t)64 * N_NODES + k0, As + 2048 + w * 512);
        gload_lds16(gB0 + k0,                        Bs + w * 512);
        gload_lds16(gB0 + (size_t)64 * N_NODES + k0, Bs + 2048 + w * 512);
        __syncthreads();
        short8 af[4], bfr[4];
        #pragma unroll
        for (int mt = 0; mt < 4; ++mt)
            af[mt] = *(const short8*)(As + (wm * 64 + mt * 16 + ar) * 32 + kq);
        #pragma unroll
        for (int nt = 0; nt < 4; ++nt)
            bfr[nt] = *(const short8*)(Bs + (wn * 64 + nt * 16 + ar) * 32 + kq);
        #pragma unroll
        for (int mt = 0; mt < 4; ++mt)
            #pragma unroll
            for (int nt = 0; nt < 4; ++nt)
                acc[mt][nt] = __builtin_amdgcn_mfma_f32_16x16x32_bf16(
                    af[mt], bfr[nt], acc[mt][nt], 0, 0, 0);
    }

    #pragma unroll
    for (int mt = 0; mt < 4; ++mt) {
        const int ibase = i0 + wm * 64 + mt * 16 + (l >> 4) * 4;
        #pragma unroll
        for (int nt = 0; nt < 4; ++nt) {
            const int j = j0 + wn * 64 + nt * 16 + (l & 15);
            const int bs = j >> 6, c = j & 63;
            #pragma unroll
            for (int r = 0; r < 4; ++r) {
                const int i = ibase + r;
                const size_t xi = ((size_t)bs * N_NODES + i) * CDIM + c;
                float g = x[xi] - dvec[i] * acc[mt][nt][r];
                G[xi] = __float2bfloat16(g);
            }
        }
    }
}

__global__ __launch_bounds__(256) void k_out(const __hip_bfloat16* __restrict__ G,
                                             const float* __restrict__ W,
                                             float* __restrict__ out) {
    __shared__ float Wt[64 * 132];
    __shared__ __hip_bfloat16 Gs[32 * 64];
    const int t = threadIdx.x;
    const int bs = blockIdx.y;
    const int i0 = blockIdx.x * 32;
    #pragma unroll
    for (int it = 0; it < 32; ++it) {
        int p = it * 256 + t;
        int h = p & 127, c = p >> 7;
        Wt[c * 132 + h] = W[h * 64 + c];
    }
    const short4* gp4 = (const short4*)(G + ((size_t)bs * N_NODES + i0) * CDIM);
    ((short4*)Gs)[t]       = gp4[t];
    ((short4*)Gs)[256 + t] = gp4[256 + t];
    __syncthreads();

    const int hg = t & 31;
    const int ig = t >> 5;
    float acc[4][4] = {};
    #pragma unroll
    for (int c = 0; c < 64; ++c) {
        float4 wv = *(const float4*)(Wt + c * 132 + hg * 4);
        #pragma unroll
        for (int ii = 0; ii < 4; ++ii) {
            float g = __bfloat162float(Gs[(ig * 4 + ii) * 64 + c]);
            acc[ii][0] += g * wv.x;
            acc[ii][1] += g * wv.y;
            acc[ii][2] += g * wv.z;
            acc[ii][3] += g * wv.w;
        }
    }
    #pragma unroll
    for (int ii = 0; ii < 4; ++ii) {
        const int i = i0 + ig * 4 + ii;
        float4 o;
        o.x = 1.f / (1.f + __expf(-acc[ii][0]));
        o.y = 1.f / (1.f + __expf(-acc[ii][1]));
        o.z = 1.f / (1.f + __expf(-acc[ii][2]));
        o.w = 1.f / (1.f + __expf(-acc[ii][3]));
        *(float4*)(out + ((size_t)bs * N_NODES + i) * HDIM + hg * 4) = o;
    }
}

extern "C" void kernel_launch(void* const* d_in, const int* in_sizes, int n_in,
                              void* d_out, int out_size, void* d_ws, size_t ws_size,
                              hipStream_t stream) {
    const float* x = (const float*)d_in[0];   // [48][4096][64]
    const float* A = (const float*)d_in[1];   // [4096][4096]
    const float* W = (const float*)d_in[2];   // [128][64]
    float* out  = (float*)d_out;              // out0: 25165824 floats
    float* outA = out + 25165824;             // A passthrough

    char* ws = (char*)d_ws;
    float* dvec = (float*)ws;
    const size_t offD = 16384;
    const size_t szAb = (size_t)16777216 * 2;     // 32 MB
    const size_t szXt = (size_t)3072 * 4096 * 2;  // 24 MB
    const size_t szG  = (size_t)48 * 4096 * 64 * 2;

    if (ws_size >= offD + szAb + szXt) {
        // fused path: Ab, Xt in workspace; no G intermediate
        __hip_bfloat16* Ab = (__hip_bfloat16*)(ws + offD);
        __hip_bfloat16* Xt = (__hip_bfloat16*)(ws + offD + szAb);
        k_prep    <<<4096, 256, 0, stream>>>(A, outA, Ab, dvec);
        k_buildXt <<<dim3(64, 48), 256, 0, stream>>>(x, dvec, Xt);
        k_gemm_out<<<dim3(24, 32), 256, 0, stream>>>(Ab, Xt, x, dvec, W, out);
    } else {
        // legacy fallback: Ab in (dead) out0 region, G in ws
        __hip_bfloat16* Ab = (__hip_bfloat16*)out;
        __hip_bfloat16* Xt = (__hip_bfloat16*)(ws + offD);
        __hip_bfloat16* G  = (__hip_bfloat16*)(ws + offD + szXt);
        k_prep    <<<4096, 256, 0, stream>>>(A, outA, Ab, dvec);
        k_buildXt <<<dim3(64, 48), 256, 0, stream>>>(x, dvec, Xt);
        k_gemm    <<<dim3(24, 32), 256, 0, stream>>>(Ab, Xt, x, dvec, G);
        k_out     <<<dim3(128, 48), 256, 0, stream>>>(G, W, out);
    }
}